// Round 5
// baseline (762.617 us; speedup 1.0000x reference)
//
#include <hip/hip_runtime.h>
#include <hip/hip_bf16.h>
#include <math.h>

#define N_VOTERS 1048576
#define NUM_CAND 32
#define EMB 128
#define NUM_ELEC 4096

typedef unsigned short u16;
typedef unsigned int u32;
typedef __attribute__((ext_vector_type(8))) short bf16x8;
typedef __attribute__((ext_vector_type(4))) float f32x4;

union U4 { u32 u[4]; bf16x8 v; };

__device__ __forceinline__ u16 f2bf(float f) {   // RNE (prep only)
    union { float f; u32 u; } v; v.f = f;
    u32 r = v.u + 0x7FFFu + ((v.u >> 16) & 1u);
    return (u16)(r >> 16);
}
// pack two floats to bf16 (round-half-up): f0 -> low16, f1 -> high16
__device__ __forceinline__ u32 pkbf(float f0, float f1) {
    u32 u0 = __float_as_uint(f0) + 0x8000u;
    u32 u1 = __float_as_uint(f1) + 0x8000u;
    return __builtin_amdgcn_perm(u1, u0, 0x07060302u);
}

// ---------------- Kernel A: transpose+convert local weights to bf16 ----------------
// w1t: [128][32] = W1^T (out-major); w2t/w3t: [128][128] (out-major) — exactly A-frag layout.
__global__ void prep_weights(const float* __restrict__ lW1, const float* __restrict__ lW2,
                             const float* __restrict__ lW3,
                             u16* __restrict__ w1t, u16* __restrict__ w2t, u16* __restrict__ w3t) {
    int tid = blockIdx.x * blockDim.x + threadIdx.x;  // 0..16383
    if (tid < 4096) {
        int n = tid >> 5, k = tid & 31;
        w1t[tid] = f2bf(lW1[k * EMB + n]);
    }
    {
        int n = tid >> 7, k = tid & 127;
        w2t[tid] = f2bf(lW2[k * EMB + n]);
        w3t[tid] = f2bf(lW3[k * EMB + n]);
    }
}

// ---------------- Kernel B: wave-independent fused local MLP ----------------
// 512 thr = 8 waves; each wave owns 64 voters end-to-end (4 subtiles of 16).
// Weights in LDS (A-operand, same-address-across-l15 -> broadcast reads, conflict-free).
// Acts stay in registers between layers: D->B transform = qd-group permute via 2 shuffles+select.
// No barriers after weight staging. Bias3 deferred to global_mlp via per-election counts.
__global__ __launch_bounds__(512, 4) void local_fused(
    const float* __restrict__ x, const int* __restrict__ idx,
    const float* __restrict__ lb1, const float* __restrict__ lb2,
    const u16* __restrict__ w1t, const u16* __restrict__ w2t, const u16* __restrict__ w3t,
    float* __restrict__ agg, float* __restrict__ cntf)
{
    __shared__ __align__(16) u16 w1s[128 * 32];    //  8 KB
    __shared__ __align__(16) u16 w2s[128 * 128];   // 32 KB
    __shared__ __align__(16) u16 w3s[128 * 128];   // 32 KB
    __shared__ __align__(16) float lb1s[128], lb2s[128];

    const int tid = threadIdx.x;

    // ---- stage weights global -> LDS (once) ----
    {
        const uint4* s2 = (const uint4*)w2t; uint4* d2 = (uint4*)w2s;
        const uint4* s3 = (const uint4*)w3t; uint4* d3 = (uint4*)w3s;
        #pragma unroll
        for (int i = 0; i < 4; ++i) {
            d2[tid + i * 512] = s2[tid + i * 512];
            d3[tid + i * 512] = s3[tid + i * 512];
        }
        ((uint4*)w1s)[tid] = ((const uint4*)w1t)[tid];
        if (tid < 128) { lb1s[tid] = lb1[tid]; lb2s[tid] = lb2[tid]; }
    }
    __syncthreads();

    const int lane = tid & 63;
    const int wv = tid >> 6;            // 8 waves
    const int qd = lane >> 4;
    const int l15 = lane & 15;
    const int vb = blockIdx.x * 512 + wv * 64;   // wave's 64 voters

    // shuffle-transform source lanes: qd_src0 = 2*(qd&1) -> lane (qd&1)*32 + l15
    const int s0l = ((qd & 1) << 5) + l15;
    const int s1l = s0l + 16;
    const bool hi = (qd >> 1) != 0;     // pick odd mt of the pair

    float fs[8][4];
    #pragma unroll
    for (int m = 0; m < 8; ++m)
        #pragma unroll
        for (int r = 0; r < 4; ++r) fs[m][r] = 0.f;
    float cntv = 0.f;
    int cur = idx[vb];

    // prefetch x for nt=0
    const float* xr0 = x + (size_t)(vb + l15) * NUM_CAND + qd * 8;
    float4 xa = *(const float4*)xr0;
    float4 xb = *(const float4*)(xr0 + 4);

    #pragma unroll 1
    for (int nt = 0; nt < 4; ++nt) {
        int sg = idx[vb + nt * 16 + l15];
        // prefetch next subtile's x
        int ntn = (nt < 3) ? nt + 1 : 3;
        const float* xrn = x + (size_t)(vb + ntn * 16 + l15) * NUM_CAND + qd * 8;
        float4 xa_n = *(const float4*)xrn;
        float4 xb_n = *(const float4*)(xrn + 4);

        U4 B1; B1.u[0] = pkbf(xa.x, xa.y); B1.u[1] = pkbf(xa.z, xa.w);
        B1.u[2] = pkbf(xb.x, xb.y); B1.u[3] = pkbf(xb.z, xb.w);

        f32x4 D[8];
        // ---- layer 1 (K=32) ----
        #pragma unroll
        for (int mt = 0; mt < 8; ++mt) {
            bf16x8 A = *(const bf16x8*)(w1s + (mt * 16 + l15) * 32 + qd * 8);
            f32x4 z = {0.f, 0.f, 0.f, 0.f};
            D[mt] = __builtin_amdgcn_mfma_f32_16x16x32_bf16(A, B1.v, z, 0, 0, 0);
        }
        u32 P[8][2];
        #pragma unroll
        for (int mt = 0; mt < 8; ++mt) {
            f32x4 b = *(const f32x4*)(lb1s + mt * 16 + qd * 4);
            float v0 = fmaxf(D[mt][0] + b[0], 0.f), v1 = fmaxf(D[mt][1] + b[1], 0.f);
            float v2 = fmaxf(D[mt][2] + b[2], 0.f), v3 = fmaxf(D[mt][3] + b[3], 0.f);
            P[mt][0] = pkbf(v0, v1); P[mt][1] = pkbf(v2, v3);
        }
        // ---- transform P -> B (layer-2 inputs) ----
        U4 Bf[4];
        #pragma unroll
        for (int kk = 0; kk < 4; ++kk) {
            u32 e0 = __shfl(P[2 * kk][0], s0l, 64), o0 = __shfl(P[2 * kk + 1][0], s0l, 64);
            u32 e1 = __shfl(P[2 * kk][1], s0l, 64), o1 = __shfl(P[2 * kk + 1][1], s0l, 64);
            u32 e2 = __shfl(P[2 * kk][0], s1l, 64), o2 = __shfl(P[2 * kk + 1][0], s1l, 64);
            u32 e3 = __shfl(P[2 * kk][1], s1l, 64), o3 = __shfl(P[2 * kk + 1][1], s1l, 64);
            Bf[kk].u[0] = hi ? o0 : e0; Bf[kk].u[1] = hi ? o1 : e1;
            Bf[kk].u[2] = hi ? o2 : e2; Bf[kk].u[3] = hi ? o3 : e3;
        }
        // ---- layer 2 (K=128) ----
        #pragma unroll
        for (int mt = 0; mt < 8; ++mt) {
            f32x4 a = {0.f, 0.f, 0.f, 0.f};
            #pragma unroll
            for (int kk = 0; kk < 4; ++kk) {
                bf16x8 A = *(const bf16x8*)(w2s + (mt * 16 + l15) * 128 + kk * 32 + qd * 8);
                a = __builtin_amdgcn_mfma_f32_16x16x32_bf16(A, Bf[kk].v, a, 0, 0, 0);
            }
            D[mt] = a;
        }
        #pragma unroll
        for (int mt = 0; mt < 8; ++mt) {
            f32x4 b = *(const f32x4*)(lb2s + mt * 16 + qd * 4);
            float v0 = fmaxf(D[mt][0] + b[0], 0.f), v1 = fmaxf(D[mt][1] + b[1], 0.f);
            float v2 = fmaxf(D[mt][2] + b[2], 0.f), v3 = fmaxf(D[mt][3] + b[3], 0.f);
            P[mt][0] = pkbf(v0, v1); P[mt][1] = pkbf(v2, v3);
        }
        // ---- transform -> layer-3 inputs ----
        #pragma unroll
        for (int kk = 0; kk < 4; ++kk) {
            u32 e0 = __shfl(P[2 * kk][0], s0l, 64), o0 = __shfl(P[2 * kk + 1][0], s0l, 64);
            u32 e1 = __shfl(P[2 * kk][1], s0l, 64), o1 = __shfl(P[2 * kk + 1][1], s0l, 64);
            u32 e2 = __shfl(P[2 * kk][0], s1l, 64), o2 = __shfl(P[2 * kk + 1][0], s1l, 64);
            u32 e3 = __shfl(P[2 * kk][1], s1l, 64), o3 = __shfl(P[2 * kk + 1][1], s1l, 64);
            Bf[kk].u[0] = hi ? o0 : e0; Bf[kk].u[1] = hi ? o1 : e1;
            Bf[kk].u[2] = hi ? o2 : e2; Bf[kk].u[3] = hi ? o3 : e3;
        }
        // ---- layer 3 (K=128), no bias (deferred), no relu ----
        #pragma unroll
        for (int mt = 0; mt < 8; ++mt) {
            f32x4 a = {0.f, 0.f, 0.f, 0.f};
            #pragma unroll
            for (int kk = 0; kk < 4; ++kk) {
                bf16x8 A = *(const bf16x8*)(w3s + (mt * 16 + l15) * 128 + kk * 32 + qd * 8);
                a = __builtin_amdgcn_mfma_f32_16x16x32_bf16(A, Bf[kk].v, a, 0, 0, 0);
            }
            D[mt] = a;
        }

        xa = xa_n; xb = xb_n;

        // ---- segment accumulation over this 16-voter subtile ----
        int first = __builtin_amdgcn_readfirstlane(sg);
        unsigned long long bal = __ballot(sg == first);
        if (bal == ~0ull) {                      // uniform subtile
            if (first != cur) {
                if (cntv > 0.f) {                // flush
                    float t[8][4];
                    #pragma unroll
                    for (int m = 0; m < 8; ++m)
                        #pragma unroll
                        for (int r = 0; r < 4; ++r) t[m][r] = fs[m][r];
                    #pragma unroll
                    for (int d = 1; d < 16; d <<= 1)
                        #pragma unroll
                        for (int m = 0; m < 8; ++m)
                            #pragma unroll
                            for (int r = 0; r < 4; ++r) t[m][r] += __shfl_xor(t[m][r], d, 16);
                    if (l15 == 0) {
                        float* p = agg + (size_t)cur * EMB + qd * 4;
                        #pragma unroll
                        for (int m = 0; m < 8; ++m)
                            #pragma unroll
                            for (int r = 0; r < 4; ++r) atomicAdd(p + m * 16 + r, t[m][r]);
                        if (qd == 0) atomicAdd(cntf + cur, cntv);
                    }
                    #pragma unroll
                    for (int m = 0; m < 8; ++m)
                        #pragma unroll
                        for (int r = 0; r < 4; ++r) fs[m][r] = 0.f;
                    cntv = 0.f;
                }
                cur = first;
            }
            #pragma unroll
            for (int m = 0; m < 8; ++m)
                #pragma unroll
                for (int r = 0; r < 4; ++r) fs[m][r] += D[m][r];
            cntv += 16.f;
        } else {                                 // boundary inside subtile (rare)
            if (cntv > 0.f) {                    // flush pending run
                float t[8][4];
                #pragma unroll
                for (int m = 0; m < 8; ++m)
                    #pragma unroll
                    for (int r = 0; r < 4; ++r) t[m][r] = fs[m][r];
                #pragma unroll
                for (int d = 1; d < 16; d <<= 1)
                    #pragma unroll
                    for (int m = 0; m < 8; ++m)
                        #pragma unroll
                        for (int r = 0; r < 4; ++r) t[m][r] += __shfl_xor(t[m][r], d, 16);
                if (l15 == 0) {
                    float* p = agg + (size_t)cur * EMB + qd * 4;
                    #pragma unroll
                    for (int m = 0; m < 8; ++m)
                        #pragma unroll
                        for (int r = 0; r < 4; ++r) atomicAdd(p + m * 16 + r, t[m][r]);
                    if (qd == 0) atomicAdd(cntf + cur, cntv);
                }
                #pragma unroll
                for (int m = 0; m < 8; ++m)
                    #pragma unroll
                    for (int r = 0; r < 4; ++r) fs[m][r] = 0.f;
                cntv = 0.f;
            }
            // segmented inclusive scan over the 16 voter lanes (sorted -> masking safe)
            float one = 1.f;
            #pragma unroll
            for (int d = 1; d < 16; d <<= 1) {
                int so = __shfl_up(sg, d, 16);
                bool ok = (l15 >= d) && (so == sg);
                #pragma unroll
                for (int m = 0; m < 8; ++m)
                    #pragma unroll
                    for (int r = 0; r < 4; ++r) {
                        float o = __shfl_up(D[m][r], d, 16);
                        if (ok) D[m][r] += o;
                    }
                float oc = __shfl_up(one, d, 16);
                if (ok) one += oc;
            }
            int sgn = __shfl_down(sg, 1, 16);
            bool isend = (l15 == 15) || (sgn != sg);
            if (isend) {
                float* p = agg + (size_t)sg * EMB + qd * 4;
                #pragma unroll
                for (int m = 0; m < 8; ++m)
                    #pragma unroll
                    for (int r = 0; r < 4; ++r) atomicAdd(p + m * 16 + r, D[m][r]);
                if (qd == 0) atomicAdd(cntf + sg, one);
            }
            cur = __shfl(sg, 15, 16);
        }
    }
    // final flush
    if (cntv > 0.f) {
        float t[8][4];
        #pragma unroll
        for (int m = 0; m < 8; ++m)
            #pragma unroll
            for (int r = 0; r < 4; ++r) t[m][r] = fs[m][r];
        #pragma unroll
        for (int d = 1; d < 16; d <<= 1)
            #pragma unroll
            for (int m = 0; m < 8; ++m)
                #pragma unroll
                for (int r = 0; r < 4; ++r) t[m][r] += __shfl_xor(t[m][r], d, 16);
        if (l15 == 0) {
            float* p = agg + (size_t)cur * EMB + qd * 4;
            #pragma unroll
            for (int m = 0; m < 8; ++m)
                #pragma unroll
                for (int r = 0; r < 4; ++r) atomicAdd(p + m * 16 + r, t[m][r]);
            if (qd == 0) atomicAdd(cntf + cur, cntv);
        }
    }
}

// ---------------- Kernel C: global MLP + log_softmax (fp32) ----------------
// Adds the deferred local bias3: agg_true[s][j] = agg[s][j] + cnt[s]*lb3[j].
__global__ __launch_bounds__(256) void global_mlp(
    const float* __restrict__ agg, const float* __restrict__ cntf, const float* __restrict__ lb3,
    const float* __restrict__ gW1, const float* __restrict__ gb1,
    const float* __restrict__ gW2, const float* __restrict__ gb2,
    const float* __restrict__ gW3, const float* __restrict__ gb3,
    float* __restrict__ out)
{
    __shared__ float actA[8 * 128];
    __shared__ float actB[8 * 128];
    __shared__ float sc[8 * 32];
    const int tid = threadIdx.x;
    const int s0 = blockIdx.x * 8;

    #pragma unroll
    for (int i = 0; i < 4; ++i) {
        int f = i * 256 + tid;
        actA[f] = agg[(size_t)s0 * 128 + f] + cntf[s0 + (f >> 7)] * lb3[f & 127];
    }
    __syncthreads();

    const int j = tid & 127, g = tid >> 7;
    {
        float acc[4];
        #pragma unroll
        for (int si = 0; si < 4; ++si) acc[si] = gb1[j];
        #pragma unroll 8
        for (int k = 0; k < 128; ++k) {
            float w = gW1[k * 128 + j];
            #pragma unroll
            for (int si = 0; si < 4; ++si) acc[si] += actA[(g * 4 + si) * 128 + k] * w;
        }
        #pragma unroll
        for (int si = 0; si < 4; ++si) actB[(g * 4 + si) * 128 + j] = fmaxf(acc[si], 0.f);
    }
    __syncthreads();
    {
        float acc[4];
        #pragma unroll
        for (int si = 0; si < 4; ++si) acc[si] = gb2[j];
        #pragma unroll 8
        for (int k = 0; k < 128; ++k) {
            float w = gW2[k * 128 + j];
            #pragma unroll
            for (int si = 0; si < 4; ++si) acc[si] += actB[(g * 4 + si) * 128 + k] * w;
        }
        #pragma unroll
        for (int si = 0; si < 4; ++si) actA[(g * 4 + si) * 128 + j] = fmaxf(acc[si], 0.f);
    }
    __syncthreads();
    {
        int c = tid & 31, sg = tid >> 5;
        float a3 = gb3[c];
        #pragma unroll 8
        for (int k = 0; k < 128; ++k) a3 += actA[sg * 128 + k] * gW3[k * 32 + c];
        sc[sg * 32 + c] = a3;
    }
    __syncthreads();
    {
        int c = tid & 31, sg = tid >> 5;
        float v = sc[sg * 32 + c];
        float m = v;
        #pragma unroll
        for (int off = 16; off >= 1; off >>= 1) m = fmaxf(m, __shfl_xor(m, off, 32));
        float e = expf(v - m);
        float sum = e;
        #pragma unroll
        for (int off = 16; off >= 1; off >>= 1) sum += __shfl_xor(sum, off, 32);
        out[(size_t)(s0 + sg) * 32 + c] = (v - m) - logf(sum);
    }
}

extern "C" void kernel_launch(void* const* d_in, const int* in_sizes, int n_in,
                              void* d_out, int out_size, void* d_ws, size_t ws_size,
                              hipStream_t stream) {
    const float* x   = (const float*)d_in[0];
    const int*   idx = (const int*)d_in[1];
    const float* lW1 = (const float*)d_in[2];
    const float* lb1 = (const float*)d_in[3];
    const float* lW2 = (const float*)d_in[4];
    const float* lb2 = (const float*)d_in[5];
    const float* lW3 = (const float*)d_in[6];
    const float* lb3 = (const float*)d_in[7];
    const float* gW1 = (const float*)d_in[8];
    const float* gb1 = (const float*)d_in[9];
    const float* gW2 = (const float*)d_in[10];
    const float* gb2 = (const float*)d_in[11];
    const float* gW3 = (const float*)d_in[12];
    const float* gb3 = (const float*)d_in[13];
    float* out = (float*)d_out;

    float* agg  = (float*)d_ws;                                 // [4096][128] fp32 = 2 MB
    float* cntf = agg + (size_t)NUM_ELEC * EMB;                 // [4096] fp32 = 16 KB
    u16* w1t = (u16*)(cntf + NUM_ELEC);                         // 16B-aligned offsets
    u16* w2t = w1t + 128 * 32;
    u16* w3t = w2t + 128 * 128;

    hipMemsetAsync(d_ws, 0, ((size_t)NUM_ELEC * EMB + NUM_ELEC) * sizeof(float), stream);
    prep_weights<<<64, 256, 0, stream>>>(lW1, lW2, lW3, w1t, w2t, w3t);
    local_fused<<<N_VOTERS / 512, 512, 0, stream>>>(x, idx, lb1, lb2, w1t, w2t, w3t, agg, cntf);
    global_mlp<<<NUM_ELEC / 8, 256, 0, stream>>>(agg, cntf, lb3, gW1, gb1, gW2, gb2, gW3, gb3, out);
}

// Round 6
// 396.244 us; speedup vs baseline: 1.9246x; 1.9246x over previous
//
#include <hip/hip_runtime.h>
#include <hip/hip_bf16.h>
#include <math.h>

#define N_VOTERS 1048576
#define NUM_CAND 32
#define EMB 128
#define NUM_ELEC 4096

typedef unsigned short u16;
typedef unsigned int u32;
typedef __attribute__((ext_vector_type(8))) short bf16x8;
typedef __attribute__((ext_vector_type(4))) float f32x4;

__device__ __forceinline__ u16 f2bf(float f) {   // RNE (prep only)
    union { float f; u32 u; } v; v.f = f;
    u32 r = v.u + 0x7FFFu + ((v.u >> 16) & 1u);
    return (u16)(r >> 16);
}
// pack two floats to bf16 (round-half-up): f0 -> low16, f1 -> high16
__device__ __forceinline__ u32 pkbf(float f0, float f1) {
    u32 u0 = __float_as_uint(f0) + 0x8000u;
    u32 u1 = __float_as_uint(f1) + 0x8000u;
    return __builtin_amdgcn_perm(u1, u0, 0x07060302u);
}

// ---------------- Kernel A: transpose+convert local weights to bf16 ----------------
// w1t: [128][32] = W1^T (out-major); w2t/w3t: [128][128] (out-major) — A-frag layout.
__global__ void prep_weights(const float* __restrict__ lW1, const float* __restrict__ lW2,
                             const float* __restrict__ lW3,
                             u16* __restrict__ w1t, u16* __restrict__ w2t, u16* __restrict__ w3t) {
    int tid = blockIdx.x * blockDim.x + threadIdx.x;  // 0..16383
    if (tid < 4096) {
        int n = tid >> 5, k = tid & 31;
        w1t[tid] = f2bf(lW1[k * EMB + n]);
    }
    {
        int n = tid >> 7, k = tid & 127;
        w2t[tid] = f2bf(lW2[k * EMB + n]);
        w3t[tid] = f2bf(lW3[k * EMB + n]);
    }
}

// ---------------- Kernel B: fused local MLP, grid-stride, weights in VGPRs ----------------
// 2048 blocks x 128 thr (2 waves). Wave w owns feature half w*64..+63 (4 m-tiles) with its
// weight A-frags pinned in VGPRs (loaded once, 512 voters amortize). Acts round-trip through
// a double-buffered LDS tile [64][136] (layout transform for free, 2 barriers/group).
// Bias1/2 ride the MFMA C operand. Layer-3 C-operand CHAINS the segment sum across subtiles
// (zero-VALU accumulation); flush = butterfly over voter lanes + l15==0 atomics at run ends.
// Bias3 deferred to global_mlp via per-election voter counts.
__global__ __launch_bounds__(128, 2) void local_fused(
    const float* __restrict__ x, const int* __restrict__ idx,
    const float* __restrict__ lb1, const float* __restrict__ lb2,
    const u16* __restrict__ w1t, const u16* __restrict__ w2t, const u16* __restrict__ w3t,
    float* __restrict__ agg, float* __restrict__ cntf)
{
    constexpr int ASTR = 136;  // u16 stride: 272B rows -> 2-way banks for b64 writes / b128 reads
    __shared__ __align__(16) u16 act1[64 * ASTR];   // 17408 B
    __shared__ __align__(16) u16 act2[64 * ASTR];   // 17408 B   (total 34816 -> 4 blocks/CU)

    const int tid = threadIdx.x;
    const int lane = tid & 63;
    const int wv = tid >> 6;        // feature half 0/1
    const int qd = lane >> 4;
    const int l15 = lane & 15;
    const int h64 = wv * 64;

    // ---- weights + biases, pinned in registers for the whole block ----
    bf16x8 w1a[4], w2a[4][4], w3a[4][4];
    f32x4 b1f[4], b2f[4];
    #pragma unroll
    for (int mt = 0; mt < 4; ++mt) {
        int mrow = h64 + mt * 16 + l15;
        w1a[mt] = *(const bf16x8*)(w1t + mrow * 32 + qd * 8);
        #pragma unroll
        for (int kk = 0; kk < 4; ++kk) {
            w2a[mt][kk] = *(const bf16x8*)(w2t + mrow * 128 + kk * 32 + qd * 8);
            w3a[mt][kk] = *(const bf16x8*)(w3t + mrow * 128 + kk * 32 + qd * 8);
        }
        b1f[mt] = *(const f32x4*)(lb1 + h64 + mt * 16 + qd * 4);
        b2f[mt] = *(const f32x4*)(lb2 + h64 + mt * 16 + qd * 4);
    }

    const int vblk = blockIdx.x * 512;   // this block's 512 contiguous voters
    f32x4 accR[4];
    #pragma unroll
    for (int mt = 0; mt < 4; ++mt) accR[mt] = (f32x4){0.f, 0.f, 0.f, 0.f};
    float cntv = 0.f;
    int cur = idx[vblk];

    // flush: butterfly-reduce accR over the 16 voter lanes, l15==0 lanes emit atomics.
    // Call only from wave-uniform control flow.
    auto flush = [&]() {
        #pragma unroll
        for (int d = 1; d < 16; d <<= 1)
            #pragma unroll
            for (int mt = 0; mt < 4; ++mt)
                #pragma unroll
                for (int r = 0; r < 4; ++r) accR[mt][r] += __shfl_xor(accR[mt][r], d, 16);
        if (l15 == 0) {
            float* p = agg + (size_t)cur * EMB + h64 + qd * 4;
            #pragma unroll
            for (int mt = 0; mt < 4; ++mt)
                #pragma unroll
                for (int r = 0; r < 4; ++r) atomicAdd(p + mt * 16 + r, accR[mt][r]);
            if (wv == 0 && qd == 0) atomicAdd(cntf + cur, cntv);
        }
        #pragma unroll
        for (int mt = 0; mt < 4; ++mt) accR[mt] = (f32x4){0.f, 0.f, 0.f, 0.f};
        cntv = 0.f;
    };

    // x prefetch for subtile 0
    const float* xp0 = x + (size_t)(vblk + l15) * NUM_CAND + qd * 8;
    float4 xa = *(const float4*)xp0;
    float4 xb = *(const float4*)(xp0 + 4);

    #pragma unroll 1
    for (int g = 0; g < 8; ++g) {
        const int vg = vblk + g * 64;
        // ---- layer 1 (K=32): x -> act1, bias in C, relu ----
        #pragma unroll
        for (int nt = 0; nt < 4; ++nt) {
            int tnext = g * 4 + nt + 1; if (tnext > 31) tnext = 31;   // clamp: stay in-block
            const float* xn = x + (size_t)(vblk + tnext * 16 + l15) * NUM_CAND + qd * 8;
            float4 xa_n = *(const float4*)xn;
            float4 xb_n = *(const float4*)(xn + 4);

            union { u32 u[4]; bf16x8 v; } B1;
            B1.u[0] = pkbf(xa.x, xa.y); B1.u[1] = pkbf(xa.z, xa.w);
            B1.u[2] = pkbf(xb.x, xb.y); B1.u[3] = pkbf(xb.z, xb.w);
            u16* wr = act1 + (nt * 16 + l15) * ASTR + h64 + qd * 4;
            #pragma unroll
            for (int mt = 0; mt < 4; ++mt) {
                f32x4 a = __builtin_amdgcn_mfma_f32_16x16x32_bf16(w1a[mt], B1.v, b1f[mt], 0, 0, 0);
                uint2 s;
                s.x = pkbf(fmaxf(a[0], 0.f), fmaxf(a[1], 0.f));
                s.y = pkbf(fmaxf(a[2], 0.f), fmaxf(a[3], 0.f));
                *(uint2*)(wr + mt * 16) = s;
            }
            xa = xa_n; xb = xb_n;
        }
        __syncthreads();
        // ---- layer 2 (K=128): act1 -> act2, bias in C, relu ----
        #pragma unroll
        for (int nt = 0; nt < 4; ++nt) {
            const u16* rd = act1 + (nt * 16 + l15) * ASTR + qd * 8;
            bf16x8 B2[4];
            #pragma unroll
            for (int kk = 0; kk < 4; ++kk) B2[kk] = *(const bf16x8*)(rd + kk * 32);
            u16* wr = act2 + (nt * 16 + l15) * ASTR + h64 + qd * 4;
            #pragma unroll
            for (int mt = 0; mt < 4; ++mt) {
                f32x4 a = b2f[mt];
                #pragma unroll
                for (int kk = 0; kk < 4; ++kk)
                    a = __builtin_amdgcn_mfma_f32_16x16x32_bf16(w2a[mt][kk], B2[kk], a, 0, 0, 0);
                uint2 s;
                s.x = pkbf(fmaxf(a[0], 0.f), fmaxf(a[1], 0.f));
                s.y = pkbf(fmaxf(a[2], 0.f), fmaxf(a[3], 0.f));
                *(uint2*)(wr + mt * 16) = s;
            }
        }
        __syncthreads();
        // ---- layer 3 (K=128): act2 -> accR via C-chaining (segment sum inside MFMA) ----
        #pragma unroll 1
        for (int nt = 0; nt < 4; ++nt) {
            int sg = idx[vg + nt * 16 + l15];
            const u16* rd = act2 + (nt * 16 + l15) * ASTR + qd * 8;
            bf16x8 B3[4];
            #pragma unroll
            for (int kk = 0; kk < 4; ++kk) B3[kk] = *(const bf16x8*)(rd + kk * 32);
            int first = __builtin_amdgcn_readfirstlane(sg);
            bool uni = (__ballot(sg == first) == ~0ull);
            if (uni) {
                if (first != cur) {
                    if (cntv > 0.f) flush();
                    cur = first;
                }
                #pragma unroll
                for (int mt = 0; mt < 4; ++mt) {
                    f32x4 a = accR[mt];
                    #pragma unroll
                    for (int kk = 0; kk < 4; ++kk)
                        a = __builtin_amdgcn_mfma_f32_16x16x32_bf16(w3a[mt][kk], B3[kk], a, 0, 0, 0);
                    accR[mt] = a;
                }
                cntv += 16.f;
            } else {                         // boundary inside subtile (rare)
                if (cntv > 0.f) flush();
                f32x4 D[4];
                #pragma unroll
                for (int mt = 0; mt < 4; ++mt) {
                    f32x4 a = {0.f, 0.f, 0.f, 0.f};
                    #pragma unroll
                    for (int kk = 0; kk < 4; ++kk)
                        a = __builtin_amdgcn_mfma_f32_16x16x32_bf16(w3a[mt][kk], B3[kk], a, 0, 0, 0);
                    D[mt] = a;
                }
                // segmented inclusive scan over 16 voter lanes (sorted -> masking safe)
                float one = 1.f;
                #pragma unroll
                for (int d = 1; d < 16; d <<= 1) {
                    int so = __shfl_up(sg, d, 16);
                    bool ok = (l15 >= d) && (so == sg);
                    #pragma unroll
                    for (int mt = 0; mt < 4; ++mt)
                        #pragma unroll
                        for (int r = 0; r < 4; ++r) {
                            float o = __shfl_up(D[mt][r], d, 16);
                            if (ok) D[mt][r] += o;
                        }
                    float oc = __shfl_up(one, d, 16);
                    if (ok) one += oc;
                }
                int sgn = __shfl_down(sg, 1, 16);
                bool isend = (l15 == 15) || (sgn != sg);
                if (isend) {
                    float* p = agg + (size_t)sg * EMB + h64 + qd * 4;
                    #pragma unroll
                    for (int mt = 0; mt < 4; ++mt)
                        #pragma unroll
                        for (int r = 0; r < 4; ++r) atomicAdd(p + mt * 16 + r, D[mt][r]);
                    if (wv == 0 && qd == 0) atomicAdd(cntf + sg, one);
                }
                cur = __shfl(sg, 15, 16);    // last voter's run continues (restarts at 0 in accR)
            }
        }
    }
    if (cntv > 0.f) flush();
}

// ---------------- Kernel C: global MLP + log_softmax (fp32) ----------------
// Adds deferred local bias3: agg_true[s][j] = agg[s][j] + cnt[s]*lb3[j].
__global__ __launch_bounds__(256) void global_mlp(
    const float* __restrict__ agg, const float* __restrict__ cntf, const float* __restrict__ lb3,
    const float* __restrict__ gW1, const float* __restrict__ gb1,
    const float* __restrict__ gW2, const float* __restrict__ gb2,
    const float* __restrict__ gW3, const float* __restrict__ gb3,
    float* __restrict__ out)
{
    __shared__ float actA[8 * 128];
    __shared__ float actB[8 * 128];
    __shared__ float sc[8 * 32];
    const int tid = threadIdx.x;
    const int s0 = blockIdx.x * 8;

    #pragma unroll
    for (int i = 0; i < 4; ++i) {
        int f = i * 256 + tid;
        actA[f] = agg[(size_t)s0 * 128 + f] + cntf[s0 + (f >> 7)] * lb3[f & 127];
    }
    __syncthreads();

    const int j = tid & 127, g = tid >> 7;
    {
        float acc[4];
        #pragma unroll
        for (int si = 0; si < 4; ++si) acc[si] = gb1[j];
        #pragma unroll 8
        for (int k = 0; k < 128; ++k) {
            float w = gW1[k * 128 + j];
            #pragma unroll
            for (int si = 0; si < 4; ++si) acc[si] += actA[(g * 4 + si) * 128 + k] * w;
        }
        #pragma unroll
        for (int si = 0; si < 4; ++si) actB[(g * 4 + si) * 128 + j] = fmaxf(acc[si], 0.f);
    }
    __syncthreads();
    {
        float acc[4];
        #pragma unroll
        for (int si = 0; si < 4; ++si) acc[si] = gb2[j];
        #pragma unroll 8
        for (int k = 0; k < 128; ++k) {
            float w = gW2[k * 128 + j];
            #pragma unroll
            for (int si = 0; si < 4; ++si) acc[si] += actB[(g * 4 + si) * 128 + k] * w;
        }
        #pragma unroll
        for (int si = 0; si < 4; ++si) actA[(g * 4 + si) * 128 + j] = fmaxf(acc[si], 0.f);
    }
    __syncthreads();
    {
        int c = tid & 31, sg = tid >> 5;
        float a3 = gb3[c];
        #pragma unroll 8
        for (int k = 0; k < 128; ++k) a3 += actA[sg * 128 + k] * gW3[k * 32 + c];
        sc[sg * 32 + c] = a3;
    }
    __syncthreads();
    {
        int c = tid & 31, sg = tid >> 5;
        float v = sc[sg * 32 + c];
        float m = v;
        #pragma unroll
        for (int off = 16; off >= 1; off >>= 1) m = fmaxf(m, __shfl_xor(m, off, 32));
        float e = expf(v - m);
        float sum = e;
        #pragma unroll
        for (int off = 16; off >= 1; off >>= 1) sum += __shfl_xor(sum, off, 32);
        out[(size_t)(s0 + sg) * 32 + c] = (v - m) - logf(sum);
    }
}

extern "C" void kernel_launch(void* const* d_in, const int* in_sizes, int n_in,
                              void* d_out, int out_size, void* d_ws, size_t ws_size,
                              hipStream_t stream) {
    const float* x   = (const float*)d_in[0];
    const int*   idx = (const int*)d_in[1];
    const float* lW1 = (const float*)d_in[2];
    const float* lb1 = (const float*)d_in[3];
    const float* lW2 = (const float*)d_in[4];
    const float* lb2 = (const float*)d_in[5];
    const float* lW3 = (const float*)d_in[6];
    const float* lb3 = (const float*)d_in[7];
    const float* gW1 = (const float*)d_in[8];
    const float* gb1 = (const float*)d_in[9];
    const float* gW2 = (const float*)d_in[10];
    const float* gb2 = (const float*)d_in[11];
    const float* gW3 = (const float*)d_in[12];
    const float* gb3 = (const float*)d_in[13];
    float* out = (float*)d_out;

    float* agg  = (float*)d_ws;                                 // [4096][128] fp32 = 2 MB
    float* cntf = agg + (size_t)NUM_ELEC * EMB;                 // [4096] fp32
    u16* w1t = (u16*)(cntf + NUM_ELEC);
    u16* w2t = w1t + 128 * 32;
    u16* w3t = w2t + 128 * 128;

    hipMemsetAsync(d_ws, 0, ((size_t)NUM_ELEC * EMB + NUM_ELEC) * sizeof(float), stream);
    prep_weights<<<64, 256, 0, stream>>>(lW1, lW2, lW3, w1t, w2t, w3t);
    local_fused<<<N_VOTERS / 512, 128, 0, stream>>>(x, idx, lb1, lb2, w1t, w2t, w3t, agg, cntf);
    global_mlp<<<NUM_ELEC / 8, 256, 0, stream>>>(agg, cntf, lb3, gW1, gb1, gW2, gb2, gW3, gb3, out);
}